// Round 3
// baseline (36634.561 us; speedup 1.0000x reference)
//
#include <hip/hip_runtime.h>

// Generic tiled GEMM: C[M,N] (fp32) = act( op(A)(MxK) @ B(KxN) + bias + (accum ? C : 0) )
// transA=1 means A is stored [K,M] row-major (compute A^T @ B).
// 64x64 C-tile per 256-thread block, 4x4 per-thread register tile, K-tile 16.
// Deterministic: fixed per-thread fp32 accumulation order, no atomics.
__global__ __launch_bounds__(256)
void gemm_kernel(const float* __restrict__ A, int lda, int transA,
                 const float* __restrict__ B, int ldb,
                 const float* __restrict__ bias,
                 float* __restrict__ C, int ldc,
                 int M, int N, int K, int act, int accum)
{
    // 68-float row stride: 272 B keeps float4 reads 16B-aligned; 2-way bank
    // aliasing only (free on CDNA4 per m136).
    __shared__ __align__(16) float As[16][68];
    __shared__ __align__(16) float Bs[16][68];
    const int tid = threadIdx.x;
    const int bm = blockIdx.y * 64;
    const int bn = blockIdx.x * 64;
    const int tr = tid >> 4;   // C rows tr*4..tr*4+3
    const int tc = tid & 15;   // C cols tc*4..tc*4+3
    float acc[4][4] = {};
    for (int k0 = 0; k0 < K; k0 += 16) {
        if (!transA) {
            #pragma unroll
            for (int i0 = 0; i0 < 4; ++i0) {
                int i = tid + i0 * 256;
                int m = i >> 4, kk = i & 15;       // consecutive tid -> consecutive k (coalesced)
                float v = 0.f;
                if (bm + m < M && k0 + kk < K)
                    v = A[(long)(bm + m) * lda + (k0 + kk)];
                As[kk][m] = v;
            }
        } else {
            #pragma unroll
            for (int i0 = 0; i0 < 4; ++i0) {
                int i = tid + i0 * 256;
                int m = i & 63, kk = i >> 6;       // consecutive tid -> consecutive m (coalesced)
                float v = 0.f;
                if (bm + m < M && k0 + kk < K)
                    v = A[(long)(k0 + kk) * lda + (bm + m)];
                As[kk][m] = v;
            }
        }
        #pragma unroll
        for (int i0 = 0; i0 < 4; ++i0) {
            int i = tid + i0 * 256;
            int n = i & 63, kk = i >> 6;
            float v = 0.f;
            if (bn + n < N && k0 + kk < K)
                v = B[(long)(k0 + kk) * ldb + (bn + n)];
            Bs[kk][n] = v;
        }
        __syncthreads();
        #pragma unroll
        for (int kk = 0; kk < 16; ++kk) {
            const float4 a4 = *reinterpret_cast<const float4*>(&As[kk][tr * 4]);
            const float4 b4 = *reinterpret_cast<const float4*>(&Bs[kk][tc * 4]);
            const float a[4] = {a4.x, a4.y, a4.z, a4.w};
            const float b[4] = {b4.x, b4.y, b4.z, b4.w};
            #pragma unroll
            for (int im = 0; im < 4; ++im)
                #pragma unroll
                for (int in = 0; in < 4; ++in)
                    acc[im][in] += a[im] * b[in];
        }
        __syncthreads();
    }
    #pragma unroll
    for (int im = 0; im < 4; ++im) {
        int m = bm + tr * 4 + im;
        if (m >= M) continue;
        #pragma unroll
        for (int in = 0; in < 4; ++in) {
            int n = bn + tc * 4 + in;
            if (n >= N) continue;
            float v = acc[im][in];
            if (bias) v += bias[n];
            if (accum) v += C[(long)m * ldc + n];
            if (act) v = fmaxf(v, 0.f);
            C[(long)m * ldc + n] = v;
        }
    }
}

__global__ __launch_bounds__(256) void copy_f(const float* __restrict__ x, float* __restrict__ y, int n) {
    int i = blockIdx.x * 256 + threadIdx.x;
    if (i < n) y[i] = x[i];
}
__global__ __launch_bounds__(256) void zero_f(float* __restrict__ x, int n) {
    int i = blockIdx.x * 256 + threadIdx.x;
    if (i < n) x[i] = 0.f;
}

// Set the one-hot entries of A_s/A_o (pre-zeroed): A_s[r, subj(r)] = 1, A_o[r, obj(r)] = 1.
// One thread per edge; distinct rows -> race-free.
__global__ __launch_bounds__(256)
void set_onehot(const int* __restrict__ pair, float* __restrict__ A_s, float* __restrict__ A_o,
                int R, int N) {
    int r = blockIdx.x * 256 + threadIdx.x;
    if (r >= R) return;
    A_s[(long)r * N + pair[2 * r]]     = 1.f;
    A_o[(long)r * N + pair[2 * r + 1]] = 1.f;
}

// Row softmax, cols <= 256, one 256-thread block (4 waves) per row.
__global__ __launch_bounds__(256)
void softmax_rows(const float* __restrict__ X, float* __restrict__ Y, int cols) {
    const int r = blockIdx.x;
    const int t = threadIdx.x;
    __shared__ float sm[4];
    float v = (t < cols) ? X[(long)r * cols + t] : -1e30f;
    float m = v;
    #pragma unroll
    for (int o = 32; o > 0; o >>= 1) m = fmaxf(m, __shfl_down(m, o));
    if ((t & 63) == 0) sm[t >> 6] = m;
    __syncthreads();
    float m0 = fmaxf(fmaxf(sm[0], sm[1]), fmaxf(sm[2], sm[3]));
    float e = (t < cols) ? expf(v - m0) : 0.f;
    float s = e;
    #pragma unroll
    for (int o = 32; o > 0; o >>= 1) s += __shfl_down(s, o);
    __syncthreads();
    if ((t & 63) == 0) sm[t >> 6] = s;
    __syncthreads();
    float s0 = sm[0] + sm[1] + sm[2] + sm[3];
    if (t < cols) Y[(long)r * cols + t] = e / s0;
}

// rcv_ip[:,0:256] = m_ie[subj], rcv_ip[:,256:512] = m_ie[obj]  (gather, deterministic)
__global__ __launch_bounds__(256)
void gather_msgs(const float* __restrict__ m_ie, const int* __restrict__ pair,
                 float* __restrict__ rcv_ip, int R) {
    int i = blockIdx.x * 256 + threadIdx.x;
    if (i >= R * 256) return;
    int r = i >> 8, c = i & 255;
    int s = pair[2 * r], o = pair[2 * r + 1];
    rcv_ip[(long)r * 768 + c]       = m_ie[(long)s * 256 + c];
    rcv_ip[(long)r * 768 + 256 + c] = m_ie[(long)o * 256 + c];
}

// gbuf layout [n, 3*1024]: cols 0:1024 = gz pre-act, 1024:2048 = gr, 2048:3072 = gh partial
__global__ __launch_bounds__(256)
void gru_ew1(const float* __restrict__ gbuf, const float* __restrict__ bW, const float* __restrict__ bU,
             const float* __restrict__ node, float* __restrict__ zbuf, float* __restrict__ rbuf, int total) {
    int i = blockIdx.x * 256 + threadIdx.x;
    if (i >= total) return;
    int col = i & 1023;
    int row = i >> 10;
    const float* g = gbuf + (long)row * 3072;
    float gz = g[col]        + bW[col]        + bU[col];
    float gr = g[1024 + col] + bW[1024 + col] + bU[1024 + col];
    float z = 1.f / (1.f + expf(-gz));
    float r = 1.f / (1.f + expf(-gr));
    zbuf[i] = z;
    rbuf[i] = r * node[i];
}
__global__ __launch_bounds__(256)
void gru_ew2(const float* __restrict__ gbuf, const float* __restrict__ bW, const float* __restrict__ bU,
             float* __restrict__ node, const float* __restrict__ zbuf, int total) {
    int i = blockIdx.x * 256 + threadIdx.x;
    if (i >= total) return;
    int col = i & 1023;
    int row = i >> 10;
    float gh = gbuf[(long)row * 3072 + 2048 + col] + bW[2048 + col] + bU[2048 + col];
    float h = tanhf(gh);
    float z = zbuf[i];
    node[i] = (1.f - z) * node[i] + z * h;
}

__global__ __launch_bounds__(256)
void transpose_f32(const float* __restrict__ X, float* __restrict__ Y, int rows, int cols) {
    int i = blockIdx.x * 256 + threadIdx.x;
    if (i >= rows * cols) return;
    int r = i / cols, c = i % cols;
    Y[(long)c * rows + r] = X[i];
}

extern "C" void kernel_launch(void* const* d_in, const int* in_sizes, int n_in,
                              void* d_out, int out_size, void* d_ws, size_t ws_size,
                              hipStream_t stream)
{
    constexpr int D = 1024, D2 = 512, D4 = 256, K3 = 3;
    constexpr int CE = 151, CR = 51, EMB = 300, NN = 512, RR = 4096;
    constexpr int MO = 1792, MI = 768, T = 3;
    (void)in_sizes; (void)n_in; (void)out_size;

    const float* roi      = (const float*)d_in[0];
    const float* uni      = (const float*)d_in[1];
    const int*   pair     = (const int*)  d_in[2];
    const float* obj_log  = (const float*)d_in[3];
    const float* emb_ent  = (const float*)d_in[4];
    const float* emb_prd  = (const float*)d_in[5];
    const float* adj_e2e  = (const float*)d_in[6];
    const float* adj_e2p  = (const float*)d_in[7];
    const float* adj_p2e  = (const float*)d_in[8];
    const float* adj_p2p  = (const float*)d_in[9];
    const float* init_ew  = (const float*)d_in[10];
    const float* init_eb  = (const float*)d_in[11];
    const float* init_pw  = (const float*)d_in[12];
    const float* init_pb  = (const float*)d_in[13];
    const float* send_w1  = (const float*)d_in[14];
    const float* send_b1  = (const float*)d_in[15];
    const float* send_w2  = (const float*)d_in[16];
    const float* send_b2  = (const float*)d_in[17];
    const float* r_oe_w1  = (const float*)d_in[18];
    const float* r_oe_b1  = (const float*)d_in[19];
    const float* r_oe_w2  = (const float*)d_in[20];
    const float* r_oe_b2  = (const float*)d_in[21];
    const float* r_op_w1  = (const float*)d_in[22];
    const float* r_op_b1  = (const float*)d_in[23];
    const float* r_op_w2  = (const float*)d_in[24];
    const float* r_op_b2  = (const float*)d_in[25];
    const float* r_ie_w1  = (const float*)d_in[26];
    const float* r_ie_b1  = (const float*)d_in[27];
    const float* r_ie_w2  = (const float*)d_in[28];
    const float* r_ie_b2  = (const float*)d_in[29];
    const float* r_ip_w1  = (const float*)d_in[30];
    const float* r_ip_b1  = (const float*)d_in[31];
    const float* r_ip_w2  = (const float*)d_in[32];
    const float* r_ip_b2  = (const float*)d_in[33];
    const float* gru_W    = (const float*)d_in[34];
    const float* gru_U    = (const float*)d_in[35];
    const float* gru_bW   = (const float*)d_in[36];
    const float* gru_bU   = (const float*)d_in[37];
    const float* out_w1   = (const float*)d_in[38];
    const float* out_b1   = (const float*)d_in[39];
    const float* out_w2   = (const float*)d_in[40];
    const float* out_b2   = (const float*)d_in[41];

    // Final logits live directly in d_out (fully rewritten every iteration).
    float* entlg = (float*)d_out;                    // [512, 151]
    float* prdlg = (float*)d_out + (long)NN * CE;    // [4096, 51]

    // ---- workspace bump allocator (fp32) ----
    float* p = (float*)d_ws;
    auto alloc = [&](long n) { float* q = p; p += n; return q; };
    float* oe    = alloc((long)CE * D);
    float* op    = alloc((long)CR * D);
    float* ie    = alloc((long)NN * D);
    float* ipn   = alloc((long)RR * D);
    float* E_ent = alloc((long)NN * CE);
    float* E_prd = alloc((long)RR * CR);
    float* m_oe  = alloc((long)CE * D4);
    float* m_op  = alloc((long)CR * D4);
    float* m_ie  = alloc((long)NN * D4);
    float* m_ip  = alloc((long)RR * D4);
    float* rc_oe = alloc((long)CE * MO);
    float* rc_op = alloc((long)CR * MO);
    float* rc_ie = alloc((long)NN * MI);
    float* rc_ip = alloc((long)RR * MI);
    float* hid   = alloc((long)RR * D);       // shared hidden buffer (max 4096x1024)
    float* msg   = alloc((long)RR * D);       // recv MLP output / GRU msg input
    float* gbuf  = alloc((long)RR * 3 * D);   // GRU gate pre-activations
    float* zbuf  = alloc((long)RR * D);
    float* rbuf  = alloc((long)RR * D);
    float* f_a   = alloc((long)RR * D);
    float* f_b   = alloc((long)CE * D);
    float* f_bT  = alloc((long)CE * D);
    size_t need = (size_t)(p - (float*)d_ws) * sizeof(float);  // ~177 MB
    if (ws_size < need) return;  // insufficient scratch: output stays poison (fails loudly)

    // One-hot A_s/A_o [RR, NN] live in gbuf's region: gbuf is only used inside
    // the GRU phase, strictly after the receive phase reads A_s/A_o.
    float* A_s = gbuf;                 // RR*NN = 2M floats
    float* A_o = gbuf + (long)RR * NN; // (gbuf holds 12M floats total)

    auto grid1 = [](long n) { return dim3((unsigned)((n + 255) / 256)); };

    auto gemm = [&](const float* A, int lda, int tA, const float* B, int ldb, const float* bias,
                    float* C, int ldc, int M, int Nn, int Kk, int act, int accum) {
        gemm_kernel<<<dim3((Nn + 63) / 64, (M + 63) / 64), 256, 0, stream>>>(
            A, lda, tA, B, ldb, bias, C, ldc, M, Nn, Kk, act, accum);
    };

    // ---- init ----
    copy_f<<<grid1((long)NN * D), 256, 0, stream>>>(roi, ie, NN * D);
    copy_f<<<grid1((long)RR * D), 256, 0, stream>>>(uni, ipn, RR * D);
    gemm(emb_ent, EMB, 0, init_ew, D, init_eb, oe, D, CE, D, EMB, 0, 0);
    gemm(emb_prd, EMB, 0, init_pw, D, init_pb, op, D, CR, D, EMB, 0, 0);
    copy_f<<<grid1((long)NN * CE), 256, 0, stream>>>(obj_log, entlg, NN * CE);
    softmax_rows<<<NN, 256, 0, stream>>>(entlg, E_ent, CE);
    zero_f<<<grid1((long)RR * CR), 256, 0, stream>>>(E_prd, RR * CR);

    for (int t = 0; t < T; ++t) {
        // ---- send MLPs (relu both layers) ----
        auto send = [&](const float* X, int n, int idx, float* out) {
            gemm(X, D, 0, send_w1 + (long)idx * D * D2, D2, send_b1 + idx * D2, hid, D2, n, D2, D, 1, 0);
            gemm(hid, D2, 0, send_w2 + (long)idx * D2 * D4, D4, send_b2 + idx * D4, out, D4, n, D4, D2, 1, 0);
        };
        send(oe, CE, 0, m_oe);
        send(op, CR, 1, m_op);
        send(ie, NN, 2, m_ie);
        send(ipn, RR, 3, m_ip);

        // ---- receive: rcv_oe = [e2e(3x256) | p2e(3x256) | E_ent^T m_ie] ----
        for (int k = 0; k < K3; ++k)
            gemm(adj_e2e + (long)k * CE * CE, CE, 1, m_oe, D4, nullptr, rc_oe + k * D4, MO, CE, D4, CE, 0, 0);
        for (int k = 0; k < K3; ++k)
            gemm(adj_p2e + (long)k * CR * CE, CE, 1, m_op, D4, nullptr, rc_oe + 3 * D4 + k * D4, MO, CE, D4, CR, 0, 0);
        gemm(E_ent, CE, 1, m_ie, D4, nullptr, rc_oe + 6 * D4, MO, CE, D4, NN, 0, 0);
        // rcv_op = [e2p | p2p | E_pred^T m_ip]
        for (int k = 0; k < K3; ++k)
            gemm(adj_e2p + (long)k * CE * CR, CR, 1, m_oe, D4, nullptr, rc_op + k * D4, MO, CR, D4, CE, 0, 0);
        for (int k = 0; k < K3; ++k)
            gemm(adj_p2p + (long)k * CR * CR, CR, 1, m_op, D4, nullptr, rc_op + 3 * D4 + k * D4, MO, CR, D4, CR, 0, 0);
        gemm(E_prd, CR, 1, m_ip, D4, nullptr, rc_op + 6 * D4, MO, CR, D4, RR, 0, 0);
        // rcv_ie = [A_s^T m_ip | A_o^T m_ip | E_ent @ m_oe]  (deterministic GEMM, no atomics)
        zero_f<<<grid1((long)2 * RR * NN), 256, 0, stream>>>(A_s, 2 * RR * NN);
        set_onehot<<<grid1(RR), 256, 0, stream>>>(pair, A_s, A_o, RR, NN);
        gemm(A_s, NN, 1, m_ip, D4, nullptr, rc_ie, MI, NN, D4, RR, 0, 0);
        gemm(A_o, NN, 1, m_ip, D4, nullptr, rc_ie + D4, MI, NN, D4, RR, 0, 0);
        gemm(E_ent, CE, 0, m_oe, D4, nullptr, rc_ie + 2 * D4, MI, NN, D4, CE, 0, 0);
        // rcv_ip = [gather subj | gather obj | E_pred @ m_op]
        gather_msgs<<<grid1((long)RR * D4), 256, 0, stream>>>(m_ie, pair, rc_ip, RR);
        gemm(E_prd, CR, 0, m_op, D4, nullptr, rc_ip + 2 * D4, MI, RR, D4, CR, 0, 0);

        // ---- recv MLP + GRU per node type ----
        auto gru = [&](float* X, int n, int tix) {
            const float* W  = gru_W  + (long)tix * 3 * D * D;
            const float* U  = gru_U  + (long)tix * 3 * D * D;
            const float* bW = gru_bW + (long)tix * 3 * D;
            const float* bU = gru_bU + (long)tix * 3 * D;
            for (int g = 0; g < 3; ++g)
                gemm(msg, D, 0, W + (long)g * D * D, D, nullptr, gbuf + g * D, 3 * D, n, D, D, 0, 0);
            gemm(X, D, 0, U, D, nullptr, gbuf, 3 * D, n, D, D, 0, 1);
            gemm(X, D, 0, U + (long)D * D, D, nullptr, gbuf + D, 3 * D, n, D, D, 0, 1);
            gru_ew1<<<grid1((long)n * D), 256, 0, stream>>>(gbuf, bW, bU, X, zbuf, rbuf, n * D);
            gemm(rbuf, D, 0, U + (long)2 * D * D, D, nullptr, gbuf + 2 * D, 3 * D, n, D, D, 0, 1);
            gru_ew2<<<grid1((long)n * D), 256, 0, stream>>>(gbuf, bW, bU, X, zbuf, n * D);
        };
        auto recv_gru = [&](const float* rcv, int n, int m_in, const float* w1, const float* b1,
                            const float* w2, const float* b2, float* X, int tix) {
            gemm(rcv, m_in, 0, w1, m_in, b1, hid, m_in, n, m_in, m_in, 1, 0);
            gemm(hid, m_in, 0, w2, D, b2, msg, D, n, D, m_in, 1, 0);
            gru(X, n, tix);
        };
        recv_gru(rc_oe, CE, MO, r_oe_w1, r_oe_b1, r_oe_w2, r_oe_b2, oe, 0);
        recv_gru(rc_op, CR, MO, r_op_w1, r_op_b1, r_op_w2, r_op_b2, op, 1);
        recv_gru(rc_ie, NN, MI, r_ie_w1, r_ie_b1, r_ie_w2, r_ie_b2, ie, 2);
        recv_gru(rc_ip, RR, MI, r_ip_w1, r_ip_b1, r_ip_w2, r_ip_b2, ipn, 3);

        // ---- output projections + logits + softmax bridges ----
        auto outmlp = [&](const float* X, int n, int idx, float* out) {
            gemm(X, D, 0, out_w1 + (long)idx * D * D, D, out_b1 + idx * D, hid, D, n, D, D, 1, 0);
            gemm(hid, D, 0, out_w2 + (long)idx * D * D, D, out_b2 + idx * D, out, D, n, D, D, 0, 0);
        };
        outmlp(ie, NN, 0, f_a);
        outmlp(oe, CE, 1, f_b);
        transpose_f32<<<grid1((long)CE * D), 256, 0, stream>>>(f_b, f_bT, CE, D);
        gemm(f_a, D, 0, f_bT, CE, nullptr, entlg, CE, NN, CE, D, 0, 0);
        outmlp(ipn, RR, 2, f_a);
        outmlp(op, CR, 3, f_b);
        transpose_f32<<<grid1((long)CR * D), 256, 0, stream>>>(f_b, f_bT, CR, D);
        gemm(f_a, D, 0, f_bT, CR, nullptr, prdlg, CR, RR, CR, D, 0, 0);
        softmax_rows<<<NN, 256, 0, stream>>>(entlg, E_ent, CE);
        softmax_rows<<<RR, 256, 0, stream>>>(prdlg, E_prd, CR);
    }
    // outputs already in d_out: ent_logits [512,151] then pred_logits [4096,51], fp32
}

// Round 4
// 16008.157 us; speedup vs baseline: 2.2885x; 2.2885x over previous
//
#include <hip/hip_runtime.h>

// Tiled batched GEMM: for z in grid.z:
//   C_z[M,N] (fp32) = act( op(A_z)(MxK) @ op(B_z)(KxN) + bias + (accum ? C_z : 0) )
// A_z = A + z*sA etc. transA: A stored [K,M]; transB: B stored [N,K].
// BM x 64 C-tile, 256 threads, (BM/16)x4 register tile, K-tile 16,
// double-buffered LDS with register staging (one barrier per K-tile).
// Deterministic: fixed per-output accumulation order (t ascending, kk ascending),
// identical for BM=64 and BM=128 — bitwise-stable across tile choices.
template<int BM>
__global__ __launch_bounds__(256)
void gemm_kernel(const float* __restrict__ A, int lda, int transA, long sA,
                 const float* __restrict__ B, int ldb, int transB, long sB,
                 const float* __restrict__ bias,
                 float* __restrict__ C, int ldc, long sC,
                 int M, int N, int K, int act, int accum)
{
    constexpr int TM = BM / 16;       // rows per thread: 4 or 8
    constexpr int AF4 = BM / 64;      // A float4s staged per thread: 1 or 2
    constexpr int LDS_A = BM + 4;     // pad: keeps float4 rows 16B-aligned, 2-way bank alias only
    __shared__ __align__(16) float As[2][16][LDS_A];
    __shared__ __align__(16) float Bs[2][16][68];
    {
        const long z = blockIdx.z;
        A += z * sA; B += z * sB; C += z * sC;
    }
    const int tid = threadIdx.x;
    const int bm = blockIdx.y * BM;
    const int bn = blockIdx.x * 64;
    const int tr = tid >> 4, tc = tid & 15;
    float acc[TM][4] = {};
    const int nt = (K + 15) / 16;
    float4 ra[AF4]; float4 rb;

    auto g_load = [&](int t) {
        const int k0 = t * 16;
        if (!transA) {
            #pragma unroll
            for (int j = 0; j < AF4; ++j) {
                int idx = tid + j * 256;            // 0..BM*4-1
                int m = idx >> 2, kc = (idx & 3) * 4;
                float4 v = {0.f, 0.f, 0.f, 0.f};
                if (bm + m < M) {
                    const float* ap = A + (long)(bm + m) * lda + k0 + kc;
                    if (k0 + kc + 3 < K) v = *(const float4*)ap;
                    else { float t4[4] = {0.f,0.f,0.f,0.f};
                           for (int q = 0; q < 4; ++q) if (k0 + kc + q < K) t4[q] = ap[q];
                           v = *(float4*)t4; }
                }
                ra[j] = v;
            }
        } else {
            #pragma unroll
            for (int j = 0; j < AF4; ++j) {
                int idx = tid + j * 256;
                int kk = idx / (BM / 4), mc = (idx % (BM / 4)) * 4;
                float4 v = {0.f, 0.f, 0.f, 0.f};
                if (k0 + kk < K) {
                    const float* ap = A + (long)(k0 + kk) * lda + bm + mc;
                    if (bm + mc + 3 < M) v = *(const float4*)ap;
                    else { float t4[4] = {0.f,0.f,0.f,0.f};
                           for (int q = 0; q < 4; ++q) if (bm + mc + q < M) t4[q] = ap[q];
                           v = *(float4*)t4; }
                }
                ra[j] = v;
            }
        }
        if (!transB) {
            int kk = tid >> 4, nc = (tid & 15) * 4;
            float4 v = {0.f, 0.f, 0.f, 0.f};
            if (k0 + kk < K) {
                const float* bp = B + (long)(k0 + kk) * ldb + bn + nc;
                if (bn + nc + 3 < N) v = *(const float4*)bp;
                else { float t4[4] = {0.f,0.f,0.f,0.f};
                       for (int q = 0; q < 4; ++q) if (bn + nc + q < N) t4[q] = bp[q];
                       v = *(float4*)t4; }
            }
            rb = v;
        } else {
            int n = tid >> 2, kc = (tid & 3) * 4;
            float4 v = {0.f, 0.f, 0.f, 0.f};
            if (bn + n < N) {
                const float* bp = B + (long)(bn + n) * ldb + k0 + kc;
                if (k0 + kc + 3 < K) v = *(const float4*)bp;
                else { float t4[4] = {0.f,0.f,0.f,0.f};
                       for (int q = 0; q < 4; ++q) if (k0 + kc + q < K) t4[q] = bp[q];
                       v = *(float4*)t4; }
            }
            rb = v;
        }
    };
    auto s_store = [&](int buf) {
        if (!transA) {
            #pragma unroll
            for (int j = 0; j < AF4; ++j) {
                int idx = tid + j * 256;
                int m = idx >> 2, kc = (idx & 3) * 4;
                As[buf][kc + 0][m] = ra[j].x; As[buf][kc + 1][m] = ra[j].y;
                As[buf][kc + 2][m] = ra[j].z; As[buf][kc + 3][m] = ra[j].w;
            }
        } else {
            #pragma unroll
            for (int j = 0; j < AF4; ++j) {
                int idx = tid + j * 256;
                int kk = idx / (BM / 4), mc = (idx % (BM / 4)) * 4;
                *(float4*)&As[buf][kk][mc] = ra[j];
            }
        }
        if (!transB) {
            int kk = tid >> 4, nc = (tid & 15) * 4;
            *(float4*)&Bs[buf][kk][nc] = rb;
        } else {
            int n = tid >> 2, kc = (tid & 3) * 4;
            Bs[buf][kc + 0][n] = rb.x; Bs[buf][kc + 1][n] = rb.y;
            Bs[buf][kc + 2][n] = rb.z; Bs[buf][kc + 3][n] = rb.w;
        }
    };

    g_load(0); s_store(0);
    __syncthreads();
    for (int t = 0; t < nt; ++t) {
        const int cur = t & 1;
        if (t + 1 < nt) g_load(t + 1);    // issue next tile's global loads before compute
        #pragma unroll
        for (int kk = 0; kk < 16; ++kk) {
            const float4 b4 = *(const float4*)&Bs[cur][kk][tc * 4];
            const float bb[4] = {b4.x, b4.y, b4.z, b4.w};
            #pragma unroll
            for (int j = 0; j < AF4; ++j) {
                const float4 a4 = *(const float4*)&As[cur][kk][tr * TM + j * 4];
                const float aa[4] = {a4.x, a4.y, a4.z, a4.w};
                #pragma unroll
                for (int im = 0; im < 4; ++im)
                    #pragma unroll
                    for (int in = 0; in < 4; ++in)
                        acc[j * 4 + im][in] += aa[im] * bb[in];
            }
        }
        if (t + 1 < nt) s_store(cur ^ 1);
        __syncthreads();
    }
    #pragma unroll
    for (int j = 0; j < AF4; ++j) {
        #pragma unroll
        for (int im = 0; im < 4; ++im) {
            int m = bm + tr * TM + j * 4 + im;
            if (m >= M) continue;
            #pragma unroll
            for (int in = 0; in < 4; ++in) {
                int n = bn + tc * 4 + in;
                if (n >= N) continue;
                float v = acc[j * 4 + im][in];
                if (bias) v += bias[n];
                if (accum) v += C[(long)m * ldc + n];
                if (act) v = fmaxf(v, 0.f);
                C[(long)m * ldc + n] = v;
            }
        }
    }
}

__global__ __launch_bounds__(256) void copy_f(const float* __restrict__ x, float* __restrict__ y, int n) {
    int i = blockIdx.x * 256 + threadIdx.x;
    if (i < n) y[i] = x[i];
}
__global__ __launch_bounds__(256) void zero_f(float* __restrict__ x, int n) {
    int i = blockIdx.x * 256 + threadIdx.x;
    if (i < n) x[i] = 0.f;
}

// Set the one-hot entries of A_s/A_o (pre-zeroed): A_s[r, subj(r)] = 1, A_o[r, obj(r)] = 1.
__global__ __launch_bounds__(256)
void set_onehot(const int* __restrict__ pair, float* __restrict__ A_s, float* __restrict__ A_o,
                int R, int N) {
    int r = blockIdx.x * 256 + threadIdx.x;
    if (r >= R) return;
    A_s[(long)r * N + pair[2 * r]]     = 1.f;
    A_o[(long)r * N + pair[2 * r + 1]] = 1.f;
}

// Row softmax, cols <= 256, one 256-thread block (4 waves) per row.
__global__ __launch_bounds__(256)
void softmax_rows(const float* __restrict__ X, float* __restrict__ Y, int cols) {
    const int r = blockIdx.x;
    const int t = threadIdx.x;
    __shared__ float sm[4];
    float v = (t < cols) ? X[(long)r * cols + t] : -1e30f;
    float m = v;
    #pragma unroll
    for (int o = 32; o > 0; o >>= 1) m = fmaxf(m, __shfl_down(m, o));
    if ((t & 63) == 0) sm[t >> 6] = m;
    __syncthreads();
    float m0 = fmaxf(fmaxf(sm[0], sm[1]), fmaxf(sm[2], sm[3]));
    float e = (t < cols) ? expf(v - m0) : 0.f;
    float s = e;
    #pragma unroll
    for (int o = 32; o > 0; o >>= 1) s += __shfl_down(s, o);
    __syncthreads();
    if ((t & 63) == 0) sm[t >> 6] = s;
    __syncthreads();
    float s0 = sm[0] + sm[1] + sm[2] + sm[3];
    if (t < cols) Y[(long)r * cols + t] = e / s0;
}

// rcv_ip[:,0:256] = m_ie[subj], rcv_ip[:,256:512] = m_ie[obj]  (gather, deterministic)
__global__ __launch_bounds__(256)
void gather_msgs(const float* __restrict__ m_ie, const int* __restrict__ pair,
                 float* __restrict__ rcv_ip, int R) {
    int i = blockIdx.x * 256 + threadIdx.x;
    if (i >= R * 256) return;
    int r = i >> 8, c = i & 255;
    int s = pair[2 * r], o = pair[2 * r + 1];
    rcv_ip[(long)r * 768 + c]       = m_ie[(long)s * 256 + c];
    rcv_ip[(long)r * 768 + 256 + c] = m_ie[(long)o * 256 + c];
}

// gbuf layout [n, 3*1024]: cols 0:1024 = gz pre-act, 1024:2048 = gr, 2048:3072 = gh partial
__global__ __launch_bounds__(256)
void gru_ew1(const float* __restrict__ gbuf, const float* __restrict__ bW, const float* __restrict__ bU,
             const float* __restrict__ node, float* __restrict__ zbuf, float* __restrict__ rbuf, int total) {
    int i = blockIdx.x * 256 + threadIdx.x;
    if (i >= total) return;
    int col = i & 1023;
    int row = i >> 10;
    const float* g = gbuf + (long)row * 3072;
    float gz = g[col]        + bW[col]        + bU[col];
    float gr = g[1024 + col] + bW[1024 + col] + bU[1024 + col];
    float z = 1.f / (1.f + expf(-gz));
    float r = 1.f / (1.f + expf(-gr));
    zbuf[i] = z;
    rbuf[i] = r * node[i];
}
__global__ __launch_bounds__(256)
void gru_ew2(const float* __restrict__ gbuf, const float* __restrict__ bW, const float* __restrict__ bU,
             float* __restrict__ node, const float* __restrict__ zbuf, int total) {
    int i = blockIdx.x * 256 + threadIdx.x;
    if (i >= total) return;
    int col = i & 1023;
    int row = i >> 10;
    float gh = gbuf[(long)row * 3072 + 2048 + col] + bW[2048 + col] + bU[2048 + col];
    float h = tanhf(gh);
    float z = zbuf[i];
    node[i] = (1.f - z) * node[i] + z * h;
}

extern "C" void kernel_launch(void* const* d_in, const int* in_sizes, int n_in,
                              void* d_out, int out_size, void* d_ws, size_t ws_size,
                              hipStream_t stream)
{
    constexpr int D = 1024, D2 = 512, D4 = 256, K3 = 3;
    constexpr int CE = 151, CR = 51, EMB = 300, NN = 512, RR = 4096;
    constexpr int MO = 1792, MI = 768, T = 3;
    (void)in_sizes; (void)n_in; (void)out_size;

    const float* roi      = (const float*)d_in[0];
    const float* uni      = (const float*)d_in[1];
    const int*   pair     = (const int*)  d_in[2];
    const float* obj_log  = (const float*)d_in[3];
    const float* emb_ent  = (const float*)d_in[4];
    const float* emb_prd  = (const float*)d_in[5];
    const float* adj_e2e  = (const float*)d_in[6];
    const float* adj_e2p  = (const float*)d_in[7];
    const float* adj_p2e  = (const float*)d_in[8];
    const float* adj_p2p  = (const float*)d_in[9];
    const float* init_ew  = (const float*)d_in[10];
    const float* init_eb  = (const float*)d_in[11];
    const float* init_pw  = (const float*)d_in[12];
    const float* init_pb  = (const float*)d_in[13];
    const float* send_w1  = (const float*)d_in[14];
    const float* send_b1  = (const float*)d_in[15];
    const float* send_w2  = (const float*)d_in[16];
    const float* send_b2  = (const float*)d_in[17];
    const float* r_oe_w1  = (const float*)d_in[18];
    const float* r_oe_b1  = (const float*)d_in[19];
    const float* r_oe_w2  = (const float*)d_in[20];
    const float* r_oe_b2  = (const float*)d_in[21];
    const float* r_op_w1  = (const float*)d_in[22];
    const float* r_op_b1  = (const float*)d_in[23];
    const float* r_op_w2  = (const float*)d_in[24];
    const float* r_op_b2  = (const float*)d_in[25];
    const float* r_ie_w1  = (const float*)d_in[26];
    const float* r_ie_b1  = (const float*)d_in[27];
    const float* r_ie_w2  = (const float*)d_in[28];
    const float* r_ie_b2  = (const float*)d_in[29];
    const float* r_ip_w1  = (const float*)d_in[30];
    const float* r_ip_b1  = (const float*)d_in[31];
    const float* r_ip_w2  = (const float*)d_in[32];
    const float* r_ip_b2  = (const float*)d_in[33];
    const float* gru_W    = (const float*)d_in[34];
    const float* gru_U    = (const float*)d_in[35];
    const float* gru_bW   = (const float*)d_in[36];
    const float* gru_bU   = (const float*)d_in[37];
    const float* out_w1   = (const float*)d_in[38];
    const float* out_b1   = (const float*)d_in[39];
    const float* out_w2   = (const float*)d_in[40];
    const float* out_b2   = (const float*)d_in[41];

    // Final logits live directly in d_out (fully rewritten every iteration).
    float* entlg = (float*)d_out;                    // [512, 151]
    float* prdlg = (float*)d_out + (long)NN * CE;    // [4096, 51]

    // ---- workspace bump allocator (fp32) ----
    float* p = (float*)d_ws;
    auto alloc = [&](long n) { float* q = p; p += n; return q; };
    float* oe    = alloc((long)CE * D);
    float* op    = alloc((long)CR * D);
    float* ie    = alloc((long)NN * D);
    float* ipn   = alloc((long)RR * D);
    float* E_ent = alloc((long)NN * CE);
    float* E_prd = alloc((long)RR * CR);
    float* m_oe  = alloc((long)CE * D4);
    float* m_op  = alloc((long)CR * D4);
    float* m_ie  = alloc((long)NN * D4);
    float* m_ip  = alloc((long)RR * D4);
    float* rc_oe = alloc((long)CE * MO);
    float* rc_op = alloc((long)CR * MO);
    float* rc_ie = alloc((long)NN * MI);
    float* rc_ip = alloc((long)RR * MI);
    float* hid   = alloc((long)RR * D);       // shared hidden buffer (max 4096x1024)
    float* msg   = alloc((long)RR * D);       // recv MLP output / GRU msg input
    float* gbuf  = alloc((long)RR * 3 * D);   // GRU gate pre-activations
    float* zbuf  = alloc((long)RR * D);
    float* rbuf  = alloc((long)RR * D);
    float* f_a   = alloc((long)RR * D);
    float* f_b   = alloc((long)CE * D);
    size_t need = (size_t)(p - (float*)d_ws) * sizeof(float);  // ~176 MB
    if (ws_size < need) return;  // insufficient scratch: output stays poison (fails loudly)

    // One-hot A_s/A_o [RR, NN] (contiguous pair) live in gbuf's region: gbuf is only
    // used in the GRU phase, strictly after the receive phase reads A_s/A_o.
    float* A_s = gbuf;                 // 2 * RR*NN = 4M floats of gbuf's 12M
    float* A_o = gbuf + (long)RR * NN;

    auto grid1 = [](long n) { return dim3((unsigned)((n + 255) / 256)); };

    // Batched GEMM launcher: picks BM=128 for large-M dispatches.
    auto gemm_b = [&](const float* A, int lda, int tA, long sA,
                      const float* B, int ldb, int tB, long sB,
                      const float* bias, float* C, int ldc, long sC,
                      int M, int Nn, int Kk, int act, int accum, int nz) {
        if (M >= 2048) {
            dim3 g((Nn + 63) / 64, (M + 127) / 128, nz);
            gemm_kernel<128><<<g, 256, 0, stream>>>(A, lda, tA, sA, B, ldb, tB, sB,
                                                    bias, C, ldc, sC, M, Nn, Kk, act, accum);
        } else {
            dim3 g((Nn + 63) / 64, (M + 63) / 64, nz);
            gemm_kernel<64><<<g, 256, 0, stream>>>(A, lda, tA, sA, B, ldb, tB, sB,
                                                   bias, C, ldc, sC, M, Nn, Kk, act, accum);
        }
    };
    auto gemm = [&](const float* A, int lda, int tA, const float* B, int ldb, const float* bias,
                    float* C, int ldc, int M, int Nn, int Kk, int act, int accum) {
        gemm_b(A, lda, tA, 0, B, ldb, 0, 0, bias, C, ldc, 0, M, Nn, Kk, act, accum, 1);
    };

    // ---- init ----
    copy_f<<<grid1((long)NN * D), 256, 0, stream>>>(roi, ie, NN * D);
    copy_f<<<grid1((long)RR * D), 256, 0, stream>>>(uni, ipn, RR * D);
    gemm(emb_ent, EMB, 0, init_ew, D, init_eb, oe, D, CE, D, EMB, 0, 0);
    gemm(emb_prd, EMB, 0, init_pw, D, init_pb, op, D, CR, D, EMB, 0, 0);
    copy_f<<<grid1((long)NN * CE), 256, 0, stream>>>(obj_log, entlg, NN * CE);
    softmax_rows<<<NN, 256, 0, stream>>>(entlg, E_ent, CE);
    zero_f<<<grid1((long)RR * CR), 256, 0, stream>>>(E_prd, RR * CR);

    for (int t = 0; t < T; ++t) {
        // ---- send MLPs (relu both layers) ----
        auto send = [&](const float* X, int n, int idx, float* out) {
            gemm(X, D, 0, send_w1 + (long)idx * D * D2, D2, send_b1 + idx * D2, hid, D2, n, D2, D, 1, 0);
            gemm(hid, D2, 0, send_w2 + (long)idx * D2 * D4, D4, send_b2 + idx * D4, out, D4, n, D4, D2, 1, 0);
        };
        send(oe, CE, 0, m_oe);
        send(op, CR, 1, m_op);
        send(ie, NN, 2, m_ie);
        send(ipn, RR, 3, m_ip);

        // ---- receive (adjacency einsums batched over k via grid.z) ----
        // rcv_oe = [e2e(3x256) | p2e(3x256) | E_ent^T m_ie]
        gemm_b(adj_e2e, CE, 1, (long)CE * CE, m_oe, D4, 0, 0, nullptr,
               rc_oe, MO, D4, CE, D4, CE, 0, 0, K3);
        gemm_b(adj_p2e, CE, 1, (long)CR * CE, m_op, D4, 0, 0, nullptr,
               rc_oe + 3 * D4, MO, D4, CE, D4, CR, 0, 0, K3);
        gemm(E_ent, CE, 1, m_ie, D4, nullptr, rc_oe + 6 * D4, MO, CE, D4, NN, 0, 0);
        // rcv_op = [e2p | p2p | E_pred^T m_ip]
        gemm_b(adj_e2p, CR, 1, (long)CE * CR, m_oe, D4, 0, 0, nullptr,
               rc_op, MO, D4, CR, D4, CE, 0, 0, K3);
        gemm_b(adj_p2p, CR, 1, (long)CR * CR, m_op, D4, 0, 0, nullptr,
               rc_op + 3 * D4, MO, D4, CR, D4, CR, 0, 0, K3);
        gemm(E_prd, CR, 1, m_ip, D4, nullptr, rc_op + 6 * D4, MO, CR, D4, RR, 0, 0);
        // rcv_ie = [A_s^T m_ip | A_o^T m_ip | E_ent @ m_oe]  (deterministic GEMM, no atomics)
        zero_f<<<grid1((long)2 * RR * NN), 256, 0, stream>>>(A_s, 2 * RR * NN);
        set_onehot<<<grid1(RR), 256, 0, stream>>>(pair, A_s, A_o, RR, NN);
        gemm_b(A_s, NN, 1, (long)RR * NN, m_ip, D4, 0, 0, nullptr,
               rc_ie, MI, D4, NN, D4, RR, 0, 0, 2);
        gemm(E_ent, CE, 0, m_oe, D4, nullptr, rc_ie + 2 * D4, MI, NN, D4, CE, 0, 0);
        // rcv_ip = [gather subj | gather obj | E_pred @ m_op]
        gather_msgs<<<grid1((long)RR * D4), 256, 0, stream>>>(m_ie, pair, rc_ip, RR);
        gemm(E_prd, CR, 0, m_op, D4, nullptr, rc_ip + 2 * D4, MI, RR, D4, CR, 0, 0);

        // ---- recv MLP + GRU per node type (gate GEMMs batched via grid.z) ----
        auto gru = [&](float* X, int n, int tix) {
            const float* W  = gru_W  + (long)tix * 3 * D * D;
            const float* U  = gru_U  + (long)tix * 3 * D * D;
            const float* bW = gru_bW + (long)tix * 3 * D;
            const float* bU = gru_bU + (long)tix * 3 * D;
            // gbuf[:, g*D:(g+1)*D] = msg @ W[g], g = 0,1,2 (one batched launch)
            gemm_b(msg, D, 0, 0, W, D, 0, (long)D * D, nullptr,
                   gbuf, 3 * D, D, n, D, D, 0, 0, 3);
            // gbuf[:, g*D:(g+1)*D] += X @ U[g], g = 0,1 (z and r gates)
            gemm_b(X, D, 0, 0, U, D, 0, (long)D * D, nullptr,
                   gbuf, 3 * D, D, n, D, D, 0, 1, 2);
            gru_ew1<<<grid1((long)n * D), 256, 0, stream>>>(gbuf, bW, bU, X, zbuf, rbuf, n * D);
            gemm(rbuf, D, 0, U + (long)2 * D * D, D, nullptr, gbuf + 2 * D, 3 * D, n, D, D, 0, 1);
            gru_ew2<<<grid1((long)n * D), 256, 0, stream>>>(gbuf, bW, bU, X, zbuf, n * D);
        };
        auto recv_gru = [&](const float* rcv, int n, int m_in, const float* w1, const float* b1,
                            const float* w2, const float* b2, float* X, int tix) {
            gemm(rcv, m_in, 0, w1, m_in, b1, hid, m_in, n, m_in, m_in, 1, 0);
            gemm(hid, m_in, 0, w2, D, b2, msg, D, n, D, m_in, 1, 0);
            gru(X, n, tix);
        };
        recv_gru(rc_oe, CE, MO, r_oe_w1, r_oe_b1, r_oe_w2, r_oe_b2, oe, 0);
        recv_gru(rc_op, CR, MO, r_op_w1, r_op_b1, r_op_w2, r_op_b2, op, 1);
        recv_gru(rc_ie, NN, MI, r_ie_w1, r_ie_b1, r_ie_w2, r_ie_b2, ie, 2);
        recv_gru(rc_ip, RR, MI, r_ip_w1, r_ip_b1, r_ip_w2, r_ip_b2, ipn, 3);

        // ---- output projections + logits (fused transB) + softmax bridges ----
        auto outmlp = [&](const float* X, int n, int idx, float* out) {
            gemm(X, D, 0, out_w1 + (long)idx * D * D, D, out_b1 + idx * D, hid, D, n, D, D, 1, 0);
            gemm(hid, D, 0, out_w2 + (long)idx * D * D, D, out_b2 + idx * D, out, D, n, D, D, 0, 0);
        };
        outmlp(ie, NN, 0, f_a);
        outmlp(oe, CE, 1, f_b);
        gemm_b(f_a, D, 0, 0, f_b, D, 1, 0, nullptr, entlg, CE, 0, NN, CE, D, 0, 0, 1);
        outmlp(ipn, RR, 2, f_a);
        outmlp(op, CR, 3, f_b);
        gemm_b(f_a, D, 0, 0, f_b, D, 1, 0, nullptr, prdlg, CR, 0, RR, CR, D, 0, 0, 1);
        softmax_rows<<<NN, 256, 0, stream>>>(entlg, E_ent, CE);
        softmax_rows<<<RR, 256, 0, stream>>>(prdlg, E_prd, CR);
    }
    // outputs already in d_out: ent_logits [512,151] then pred_logits [4096,51], fp32
}